// Round 1
// baseline (1657.964 us; speedup 1.0000x reference)
//
#include <hip/hip_runtime.h>
#include <hip/hip_bf16.h>

#define HQn 16
#define HKVn 4
#define HDn 64
#define Bn 2
#define Sn 1024
#define Hn 1024
#define En 8
#define In 2048
#define Tn 2048
#define EPSf 1e-6f

// ---------------- helpers ----------------
__device__ __forceinline__ unsigned short f2bf(float f) {
  unsigned u = __float_as_uint(f);
  u += 0x7fffu + ((u >> 16) & 1u);
  return (unsigned short)(u >> 16);
}
__device__ __forceinline__ float bf2f(unsigned short u) {
  return __uint_as_float(((unsigned)u) << 16);
}

// ---------------- RMSNorm over H=1024, one block per row ----------------
__global__ __launch_bounds__(256) void k_rmsnorm(
    const float* __restrict__ x, const float* __restrict__ w,
    float* __restrict__ out) {
  int row = blockIdx.x, tid = threadIdx.x;
  size_t off = (size_t)row * Hn + tid * 4;
  float4 v = *(const float4*)(x + off);
  float ss = v.x * v.x + v.y * v.y + v.z * v.z + v.w * v.w;
#pragma unroll
  for (int o = 32; o > 0; o >>= 1) ss += __shfl_xor(ss, o);
  __shared__ float ls[4];
  if ((tid & 63) == 0) ls[tid >> 6] = ss;
  __syncthreads();
  float tot = ls[0] + ls[1] + ls[2] + ls[3];
  float sc = rsqrtf(tot * (1.0f / Hn) + EPSf);
  float4 wv = *(const float4*)(w + tid * 4);
  float4 o4;
  o4.x = v.x * sc * wv.x; o4.y = v.y * sc * wv.y;
  o4.z = v.z * sc * wv.z; o4.w = v.w * sc * wv.w;
  *(float4*)(out + off) = o4;
}

// ---------------- residual add + RMSNorm ----------------
__global__ __launch_bounds__(256) void k_resid_norm(
    const float* __restrict__ x, const float* __restrict__ y,
    const float* __restrict__ w, float* __restrict__ x2out,
    float* __restrict__ tout) {
  int row = blockIdx.x, tid = threadIdx.x;
  size_t off = (size_t)row * Hn + tid * 4;
  float4 xv = *(const float4*)(x + off);
  float4 yv = *(const float4*)(y + off);
  float4 s;
  s.x = xv.x + yv.x; s.y = xv.y + yv.y; s.z = xv.z + yv.z; s.w = xv.w + yv.w;
  *(float4*)(x2out + off) = s;
  float ss = s.x * s.x + s.y * s.y + s.z * s.z + s.w * s.w;
#pragma unroll
  for (int o = 32; o > 0; o >>= 1) ss += __shfl_xor(ss, o);
  __shared__ float ls[4];
  if ((tid & 63) == 0) ls[tid >> 6] = ss;
  __syncthreads();
  float tot = ls[0] + ls[1] + ls[2] + ls[3];
  float sc = rsqrtf(tot * (1.0f / Hn) + EPSf);
  float4 wv4 = *(const float4*)(w + tid * 4);
  float4 t4;
  t4.x = s.x * sc * wv4.x; t4.y = s.y * sc * wv4.y;
  t4.z = s.z * sc * wv4.z; t4.w = s.w * sc * wv4.w;
  *(float4*)(tout + off) = t4;
}

// ---------------- generic f32 GEMM: C(MxN) = A(MxK) @ B(KxN), 64x64 tile ----------------
__global__ __launch_bounds__(256) void k_gemm(
    const float* __restrict__ A, const float* __restrict__ B,
    float* __restrict__ C, int M, int N, int K) {
  __shared__ float As[16][68];
  __shared__ float Bs[16][64];
  int tid = threadIdx.x;
  int n0 = blockIdx.x * 64, m0 = blockIdx.y * 64;
  int tx = tid & 15, ty = tid >> 4;
  int arow = tid >> 2, ak = (tid & 3) * 4;
  int brow = tid >> 4, bcol = (tid & 15) * 4;
  float acc[4][4] = {};
  const float* Ap = A + (size_t)(m0 + arow) * K + ak;
  const float* Bp = B + (size_t)brow * N + n0 + bcol;
  for (int kb = 0; kb < K; kb += 16) {
    float4 a4 = *(const float4*)(Ap + kb);
    float4 b4 = *(const float4*)(Bp + (size_t)kb * N);
    __syncthreads();
    As[ak + 0][arow] = a4.x; As[ak + 1][arow] = a4.y;
    As[ak + 2][arow] = a4.z; As[ak + 3][arow] = a4.w;
    *(float4*)&Bs[brow][bcol] = b4;
    __syncthreads();
#pragma unroll
    for (int k = 0; k < 16; k++) {
      float4 av = *(const float4*)&As[k][ty * 4];
      float4 bv = *(const float4*)&Bs[k][tx * 4];
      float ar[4] = {av.x, av.y, av.z, av.w};
      float br[4] = {bv.x, bv.y, bv.z, bv.w};
#pragma unroll
      for (int i = 0; i < 4; i++)
#pragma unroll
        for (int j = 0; j < 4; j++)
          acc[i][j] = fmaf(ar[i], br[j], acc[i][j]);
    }
  }
#pragma unroll
  for (int i = 0; i < 4; i++) {
    float4 o4 = {acc[i][0], acc[i][1], acc[i][2], acc[i][3]};
    *(float4*)(C + (size_t)(m0 + ty * 4 + i) * N + n0 + tx * 4) = o4;
  }
}

// ---------------- q/k head-RMSNorm + RoPE, v transpose; writes k,v outputs ----------------
__global__ __launch_bounds__(256) void k_qkv_post(
    const float* __restrict__ q_raw, const float* __restrict__ k_raw,
    const float* __restrict__ v_raw, const float* __restrict__ qn_w,
    const float* __restrict__ kn_w, const float* __restrict__ freq,
    float* __restrict__ q_t, float* __restrict__ k_t, float* __restrict__ v_t,
    float* __restrict__ k_out, float* __restrict__ v_out) {
  int gw = blockIdx.x * 4 + (threadIdx.x >> 6);  // 0 .. Tn*24-1
  int lane = threadIdx.x & 63;
  int token = gw / 24;
  int hh = gw % 24;
  int b = token / Sn, s = token % Sn;
  if (hh >= 20) {  // v head: plain copy + transpose
    int h = hh - 20;
    float v = v_raw[(size_t)token * (HKVn * HDn) + h * HDn + lane];
    v_t[(((size_t)(b * HKVn + h)) * Sn + s) * HDn + lane] = v;
    v_out[(size_t)token * (HKVn * HDn) + h * HDn + lane] = v;
    return;
  }
  bool isq = hh < 16;
  int h = isq ? hh : hh - 16;
  float val = isq ? q_raw[(size_t)token * (HQn * HDn) + h * HDn + lane]
                  : k_raw[(size_t)token * (HKVn * HDn) + h * HDn + lane];
  float ss = val * val;
#pragma unroll
  for (int o = 32; o > 0; o >>= 1) ss += __shfl_xor(ss, o);
  float scn = rsqrtf(ss * (1.0f / HDn) + EPSf);
  float w = isq ? qn_w[lane] : kn_w[lane];
  float xn = val * scn * w;
  float f = freq[(size_t)s * (HDn / 2) + (lane & 31)];
  float c = cosf(f), sn = sinf(f);
  float partner = __shfl_xor(xn, 32);
  float out = (lane < 32) ? (xn * c - partner * sn) : (partner * sn + xn * c);
  if (isq) {
    q_t[(((size_t)(b * HQn + h)) * Sn + s) * HDn + lane] = out;
  } else {
    k_t[(((size_t)(b * HKVn + h)) * Sn + s) * HDn + lane] = out;
    k_out[(size_t)token * (HKVn * HDn) + h * HDn + lane] = out;
  }
}

// ---------------- causal GQA flash attention: 1 wave per query, 8 q/block ----------------
#define AQ 8
__global__ __launch_bounds__(512) void k_attn(
    const float* __restrict__ q_t, const float* __restrict__ k_t,
    const float* __restrict__ v_t, float* __restrict__ y) {
  __shared__ float Kt[HDn][65];  // transposed K chunk, padded
  __shared__ float Vs[64][65];   // V chunk, padded
  __shared__ float qs[AQ][HDn];
  __shared__ float ps[AQ][64];
  int bid = blockIdx.x;
  int nqt = Sn / AQ;  // 128
  int qt = bid % nqt;
  int h = (bid / nqt) % HQn;
  int b = bid / (nqt * HQn);
  int kvh = h >> 2;
  int w = threadIdx.x >> 6, lane = threadIdx.x & 63;
  int q = qt * AQ + w;
  const float* Kp = k_t + ((size_t)(b * HKVn + kvh) * Sn) * HDn;
  const float* Vp = v_t + ((size_t)(b * HKVn + kvh) * Sn) * HDn;
  qs[w][lane] = q_t[(((size_t)(b * HQn + h)) * Sn + q) * HDn + lane];
  float m = -1e30f, l = 0.f, o = 0.f;  // lane owns output dim `lane`
  int kmax = qt * AQ + (AQ - 1);
  for (int kk = 0; kk <= kmax; kk += 64) {
    __syncthreads();  // previous chunk compute done
#pragma unroll
    for (int rep = 0; rep < 2; rep++) {
      int vv = threadIdx.x + rep * 512;
      int row = vv >> 4;
      int d0 = (vv & 15) * 4;
      float4 k4 = *(const float4*)(Kp + (size_t)(kk + row) * HDn + d0);
      Kt[d0 + 0][row] = k4.x; Kt[d0 + 1][row] = k4.y;
      Kt[d0 + 2][row] = k4.z; Kt[d0 + 3][row] = k4.w;
      float4 v4 = *(const float4*)(Vp + (size_t)(kk + row) * HDn + d0);
      Vs[row][d0 + 0] = v4.x; Vs[row][d0 + 1] = v4.y;
      Vs[row][d0 + 2] = v4.z; Vs[row][d0 + 3] = v4.w;
    }
    __syncthreads();
    if (kk <= q) {
      float sc = 0.f;  // score for key kk+lane
#pragma unroll
      for (int d4 = 0; d4 < HDn; d4 += 4) {
        float4 q4 = *(const float4*)&qs[w][d4];
        sc = fmaf(q4.x, Kt[d4 + 0][lane], sc);
        sc = fmaf(q4.y, Kt[d4 + 1][lane], sc);
        sc = fmaf(q4.z, Kt[d4 + 2][lane], sc);
        sc = fmaf(q4.w, Kt[d4 + 3][lane], sc);
      }
      sc *= 0.125f;
      int key = kk + lane;
      if (key > q) sc = -1e30f;
      float mx = sc;
#pragma unroll
      for (int off = 32; off > 0; off >>= 1) mx = fmaxf(mx, __shfl_xor(mx, off));
      float mn = fmaxf(m, mx);
      float p = (key > q) ? 0.f : __expf(sc - mn);
      float rescale = __expf(m - mn);
      float psum = p;
#pragma unroll
      for (int off = 32; off > 0; off >>= 1) psum += __shfl_xor(psum, off);
      l = l * rescale + psum;
      m = mn;
      ps[w][lane] = p;  // same-wave LDS: ordered
      o *= rescale;
#pragma unroll
      for (int k4 = 0; k4 < 64; k4 += 4) {
        float4 p4 = *(const float4*)&ps[w][k4];
        o = fmaf(p4.x, Vs[k4 + 0][lane], o);
        o = fmaf(p4.y, Vs[k4 + 1][lane], o);
        o = fmaf(p4.z, Vs[k4 + 2][lane], o);
        o = fmaf(p4.w, Vs[k4 + 3][lane], o);
      }
    }
  }
  y[((size_t)(b * Sn + q)) * (HQn * HDn) + h * HDn + lane] = o / l;
}

// ---------------- MoE router: softmax top-2, one wave per token ----------------
__global__ __launch_bounds__(256) void k_router(
    const float* __restrict__ t, const float* __restrict__ gw_,
    int* __restrict__ idx, float* __restrict__ val, int* __restrict__ cnt) {
  int tok = blockIdx.x * 4 + (threadIdx.x >> 6);
  int lane = threadIdx.x & 63;
  const float* tr = t + (size_t)tok * Hn;
  float s[8] = {0, 0, 0, 0, 0, 0, 0, 0};
  for (int hh = lane; hh < Hn; hh += 64) {
    float tv = tr[hh];
    float4 g0 = *(const float4*)(gw_ + hh * 8);
    float4 g1 = *(const float4*)(gw_ + hh * 8 + 4);
    s[0] = fmaf(tv, g0.x, s[0]); s[1] = fmaf(tv, g0.y, s[1]);
    s[2] = fmaf(tv, g0.z, s[2]); s[3] = fmaf(tv, g0.w, s[3]);
    s[4] = fmaf(tv, g1.x, s[4]); s[5] = fmaf(tv, g1.y, s[5]);
    s[6] = fmaf(tv, g1.z, s[6]); s[7] = fmaf(tv, g1.w, s[7]);
  }
#pragma unroll
  for (int e = 0; e < 8; e++)
#pragma unroll
    for (int off = 32; off > 0; off >>= 1) s[e] += __shfl_xor(s[e], off);
  if (lane == 0) {
    float mx = s[0];
    for (int e = 1; e < 8; e++) mx = fmaxf(mx, s[e]);
    float p[8];
    for (int e = 0; e < 8; e++) p[e] = __expf(s[e] - mx);
    int e0 = 0;
    for (int e = 1; e < 8; e++) if (p[e] > p[e0]) e0 = e;
    int e1 = (e0 == 0) ? 1 : 0;
    for (int e = 0; e < 8; e++) if (e != e0 && p[e] > p[e1]) e1 = e;
    float v0 = p[e0], v1 = p[e1], inv = 1.f / (v0 + v1);
    idx[tok * 2] = e0; idx[tok * 2 + 1] = e1;
    val[tok * 2] = v0 * inv; val[tok * 2 + 1] = v1 * inv;
    atomicAdd(&cnt[e0], 1); atomicAdd(&cnt[e1], 1);
  }
}

__global__ void k_scan(const int* __restrict__ cnt, int* __restrict__ offs,
                       int* __restrict__ cursor) {
  if (threadIdx.x == 0) {
    int run = 0;
    for (int e = 0; e < En; e++) { offs[e] = run; cursor[e] = run; run += cnt[e]; }
  }
}

__global__ __launch_bounds__(256) void k_scatter(
    const int* __restrict__ idx, const float* __restrict__ val,
    int* __restrict__ cursor, int* __restrict__ tokl, float* __restrict__ wvl) {
  int t = blockIdx.x * 256 + threadIdx.x;
#pragma unroll
  for (int slot = 0; slot < 2; slot++) {
    int e = idx[t * 2 + slot];
    int pos = atomicAdd(&cursor[e], 1);
    tokl[pos] = t;
    wvl[pos] = val[t * 2 + slot];
  }
}

// ---------------- MoE GEMM1: act = silu(t@w1[e]) * (t@w3[e]), gathered rows ----------------
__global__ __launch_bounds__(256) void k_moe_gemm13(
    const float* __restrict__ t, const float* __restrict__ w1,
    const float* __restrict__ w3, const int* __restrict__ cnt,
    const int* __restrict__ offs, const int* __restrict__ tokl,
    unsigned short* __restrict__ act) {
  int e = blockIdx.z, mt = blockIdx.y;
  int n_e = cnt[e];
  if (mt * 64 >= n_e) return;
  int base = offs[e];
  int n0 = blockIdx.x * 64;
  __shared__ float As[16][68];
  __shared__ float B1s[16][64];
  __shared__ float B3s[16][64];
  __shared__ int toks[64];
  int tid = threadIdx.x;
  if (tid < 64) {
    int rr = mt * 64 + tid;
    toks[tid] = (rr < n_e) ? tokl[base + rr] : -1;
  }
  __syncthreads();
  int tx = tid & 15, ty = tid >> 4;
  int arow = tid >> 2, ak = (tid & 3) * 4;
  int brow = tid >> 4, bcol = (tid & 15) * 4;
  int tk = toks[arow];
  const float* w1e = w1 + (size_t)e * Hn * In;
  const float* w3e = w3 + (size_t)e * Hn * In;
  float au[4][4] = {}, ag[4][4] = {};
  for (int kb = 0; kb < Hn; kb += 16) {
    float4 a4 = make_float4(0.f, 0.f, 0.f, 0.f);
    if (tk >= 0) a4 = *(const float4*)(t + (size_t)tk * Hn + kb + ak);
    float4 b14 = *(const float4*)(w1e + (size_t)(kb + brow) * In + n0 + bcol);
    float4 b34 = *(const float4*)(w3e + (size_t)(kb + brow) * In + n0 + bcol);
    __syncthreads();
    As[ak + 0][arow] = a4.x; As[ak + 1][arow] = a4.y;
    As[ak + 2][arow] = a4.z; As[ak + 3][arow] = a4.w;
    *(float4*)&B1s[brow][bcol] = b14;
    *(float4*)&B3s[brow][bcol] = b34;
    __syncthreads();
#pragma unroll
    for (int k = 0; k < 16; k++) {
      float4 av = *(const float4*)&As[k][ty * 4];
      float4 b1v = *(const float4*)&B1s[k][tx * 4];
      float4 b3v = *(const float4*)&B3s[k][tx * 4];
      float ar[4] = {av.x, av.y, av.z, av.w};
      float b1r[4] = {b1v.x, b1v.y, b1v.z, b1v.w};
      float b3r[4] = {b3v.x, b3v.y, b3v.z, b3v.w};
#pragma unroll
      for (int i = 0; i < 4; i++)
#pragma unroll
        for (int j = 0; j < 4; j++) {
          au[i][j] = fmaf(ar[i], b1r[j], au[i][j]);
          ag[i][j] = fmaf(ar[i], b3r[j], ag[i][j]);
        }
    }
  }
#pragma unroll
  for (int i = 0; i < 4; i++) {
    int rr = mt * 64 + ty * 4 + i;
    if (rr < n_e) {
      size_t ro = (size_t)(base + rr) * In + n0 + tx * 4;
#pragma unroll
      for (int j = 0; j < 4; j++) {
        float u = au[i][j];
        float sv = u / (1.f + __expf(-u));  // silu
        act[ro + j] = f2bf(sv * ag[i][j]);
      }
    }
  }
}

// ---------------- MoE GEMM2: out0 += gate * (act @ w2[e]) ----------------
__global__ __launch_bounds__(256) void k_moe_gemm2(
    const unsigned short* __restrict__ act, const float* __restrict__ w2,
    const int* __restrict__ cnt, const int* __restrict__ offs,
    const int* __restrict__ tokl, const float* __restrict__ wvl,
    float* __restrict__ out0) {
  int e = blockIdx.z, mt = blockIdx.y;
  int n_e = cnt[e];
  if (mt * 64 >= n_e) return;
  int base = offs[e];
  int n0 = blockIdx.x * 64;
  __shared__ float As[16][68];
  __shared__ float Bs[16][64];
  int tid = threadIdx.x;
  int tx = tid & 15, ty = tid >> 4;
  int arow = tid >> 2, ak = (tid & 3) * 4;
  int brow = tid >> 4, bcol = (tid & 15) * 4;
  int rr_a = mt * 64 + arow;
  bool va = rr_a < n_e;
  const unsigned short* ap = act + (size_t)(base + rr_a) * In + ak;
  const float* w2e = w2 + (size_t)e * In * Hn;
  float acc[4][4] = {};
  for (int kb = 0; kb < In; kb += 16) {
    float a0 = 0, a1 = 0, a2 = 0, a3 = 0;
    if (va) {
      ushort4 u4 = *(const ushort4*)(ap + kb);
      a0 = bf2f(u4.x); a1 = bf2f(u4.y); a2 = bf2f(u4.z); a3 = bf2f(u4.w);
    }
    float4 b4 = *(const float4*)(w2e + (size_t)(kb + brow) * Hn + n0 + bcol);
    __syncthreads();
    As[ak + 0][arow] = a0; As[ak + 1][arow] = a1;
    As[ak + 2][arow] = a2; As[ak + 3][arow] = a3;
    *(float4*)&Bs[brow][bcol] = b4;
    __syncthreads();
#pragma unroll
    for (int k = 0; k < 16; k++) {
      float4 av = *(const float4*)&As[k][ty * 4];
      float4 bv = *(const float4*)&Bs[k][tx * 4];
      float ar[4] = {av.x, av.y, av.z, av.w};
      float br[4] = {bv.x, bv.y, bv.z, bv.w};
#pragma unroll
      for (int i = 0; i < 4; i++)
#pragma unroll
        for (int j = 0; j < 4; j++)
          acc[i][j] = fmaf(ar[i], br[j], acc[i][j]);
    }
  }
#pragma unroll
  for (int i = 0; i < 4; i++) {
    int rr = mt * 64 + ty * 4 + i;
    if (rr < n_e) {
      int tk = tokl[base + rr];
      float wv = wvl[base + rr];
      float* orow = out0 + (size_t)tk * Hn + n0 + tx * 4;
#pragma unroll
      for (int j = 0; j < 4; j++) atomicAdd(orow + j, wv * acc[i][j]);
    }
  }
}

// ---------------- launch ----------------
extern "C" void kernel_launch(void* const* d_in, const int* in_sizes, int n_in,
                              void* d_out, int out_size, void* d_ws, size_t ws_size,
                              hipStream_t stream) {
  (void)in_sizes; (void)n_in; (void)out_size; (void)ws_size;
  const float* x      = (const float*)d_in[0];
  const float* freq   = (const float*)d_in[1];
  const float* n1w    = (const float*)d_in[2];
  const float* n2w    = (const float*)d_in[3];
  const float* wq     = (const float*)d_in[4];
  const float* wk     = (const float*)d_in[5];
  const float* wvp    = (const float*)d_in[6];
  const float* wo     = (const float*)d_in[7];
  const float* qn_w   = (const float*)d_in[8];
  const float* kn_w   = (const float*)d_in[9];
  const float* gate_w = (const float*)d_in[10];
  const float* w1     = (const float*)d_in[11];
  const float* w2     = (const float*)d_in[12];
  const float* w3     = (const float*)d_in[13];

  float* out0  = (float*)d_out;
  float* k_out = out0 + (size_t)Tn * Hn;            // 2,097,152
  float* v_out = k_out + (size_t)Tn * HKVn * HDn;   // +524,288

  float* ws = (float*)d_ws;
  float* hn    = ws;                  // 2M floats (reused as t_norm)
  float* q_raw = ws + 2097152;        // 2M (reused as y_att)
  float* k_raw = ws + 4194304;        // 512K
  float* v_raw = ws + 4718592;        // 512K
  float* q_t   = ws + 5242880;        // 2M (reused as y2)
  float* k_t   = ws + 7340032;        // 512K
  float* v_t   = ws + 7864320;        // 512K
  unsigned short* act = (unsigned short*)(ws + 8388608);  // 4096x2048 bf16 = 4M float slots
  float* Rb = ws + 12582912;
  int*   idxb   = (int*)Rb;           // 4096
  float* valb   = Rb + 4096;          // 4096
  int*   cnt    = (int*)(Rb + 8192);  // 8
  int*   offs   = (int*)(Rb + 8200);  // 8
  int*   cursor = (int*)(Rb + 8208);  // 8
  int*   tokl   = (int*)(Rb + 8224);  // 4096
  float* wvl    = Rb + 12320;         // 4096

  float* t_norm = hn;
  float* y_att  = q_raw;
  float* y2     = q_t;

  hipMemsetAsync(cnt, 0, 8 * sizeof(int), stream);

  k_rmsnorm<<<Tn, 256, 0, stream>>>(x, n1w, hn);
  k_gemm<<<dim3(16, 32), 256, 0, stream>>>(hn, wq, q_raw, Tn, 1024, 1024);
  k_gemm<<<dim3(4, 32), 256, 0, stream>>>(hn, wk, k_raw, Tn, 256, 1024);
  k_gemm<<<dim3(4, 32), 256, 0, stream>>>(hn, wvp, v_raw, Tn, 256, 1024);
  k_qkv_post<<<(Tn * 24) / 4, 256, 0, stream>>>(q_raw, k_raw, v_raw, qn_w, kn_w,
                                                freq, q_t, k_t, v_t, k_out, v_out);
  k_attn<<<Bn * HQn * (Sn / AQ), 512, 0, stream>>>(q_t, k_t, v_t, y_att);
  k_gemm<<<dim3(16, 32), 256, 0, stream>>>(y_att, wo, y2, Tn, 1024, 1024);
  k_resid_norm<<<Tn, 256, 0, stream>>>(x, y2, n2w, out0, t_norm);
  k_router<<<Tn / 4, 256, 0, stream>>>(t_norm, gate_w, idxb, valb, cnt);
  k_scan<<<1, 64, 0, stream>>>(cnt, offs, cursor);
  k_scatter<<<Tn / 256, 256, 0, stream>>>(idxb, valb, cursor, tokl, wvl);
  k_moe_gemm13<<<dim3(In / 64, Tn / 64, En), 256, 0, stream>>>(t_norm, w1, w3, cnt,
                                                               offs, tokl, act);
  k_moe_gemm2<<<dim3(Hn / 64, Tn / 64, En), 256, 0, stream>>>(act, w2, cnt, offs,
                                                              tokl, wvl, out0);
}

// Round 3
// 1132.900 us; speedup vs baseline: 1.4635x; 1.4635x over previous
//
#include <hip/hip_runtime.h>
#include <hip/hip_bf16.h>

#define HQn 16
#define HKVn 4
#define HDn 64
#define Bn 2
#define Sn 1024
#define Hn 1024
#define En 8
#define In 2048
#define Tn 2048
#define EPSf 1e-6f

typedef __attribute__((ext_vector_type(8))) short bf16x8;
typedef __attribute__((ext_vector_type(4))) float f32x4;

// ---------------- helpers ----------------
__device__ __forceinline__ unsigned short f2bf(float f) {
  unsigned u = __float_as_uint(f);
  u += 0x7fffu + ((u >> 16) & 1u);
  return (unsigned short)(u >> 16);
}
__device__ __forceinline__ float bf2f(unsigned short u) {
  return __uint_as_float(((unsigned)u) << 16);
}
__device__ __forceinline__ void gll16(const void* g, void* l) {
  __builtin_amdgcn_global_load_lds(
      (const __attribute__((address_space(1))) void*)g,
      (__attribute__((address_space(3))) void*)l, 16, 0, 0);
}

// ---------------- transpose + f32->bf16: src[Z][R][C] -> dst[Z][C][R] ----------------
__global__ __launch_bounds__(256) void k_tcvt(
    const float* __restrict__ src, unsigned short* __restrict__ dst,
    int R, int C, size_t sZ, size_t dZ) {
  src += (size_t)blockIdx.z * sZ;
  dst += (size_t)blockIdx.z * dZ;
  int c0 = blockIdx.x * 64, r0 = blockIdx.y * 64;
  __shared__ float t[64][65];
  int tid = threadIdx.x;
  int lr = tid >> 4, lc = (tid & 15) * 4;
#pragma unroll
  for (int p = 0; p < 4; p++) {
    float4 v = *(const float4*)(src + (size_t)(r0 + lr + p * 16) * C + c0 + lc);
    t[lr + p * 16][lc + 0] = v.x; t[lr + p * 16][lc + 1] = v.y;
    t[lr + p * 16][lc + 2] = v.z; t[lr + p * 16][lc + 3] = v.w;
  }
  __syncthreads();
  int oc = tid >> 2;
  int seg = (tid & 3) * 16;
  unsigned pk[8];
#pragma unroll
  for (int j = 0; j < 8; j++) {
    unsigned short lo = f2bf(t[seg + 2 * j][oc]);
    unsigned short hi = f2bf(t[seg + 2 * j + 1][oc]);
    pk[j] = (unsigned)lo | ((unsigned)hi << 16);
  }
  uint4* dp = (uint4*)(dst + (size_t)(c0 + oc) * R + r0 + seg);
  dp[0] = make_uint4(pk[0], pk[1], pk[2], pk[3]);
  dp[1] = make_uint4(pk[4], pk[5], pk[6], pk[7]);
}

// ---------------- RMSNorm over H=1024, one block per row (f32 out) ----------------
__global__ __launch_bounds__(256) void k_rmsnorm(
    const float* __restrict__ x, const float* __restrict__ w,
    float* __restrict__ out) {
  int row = blockIdx.x, tid = threadIdx.x;
  size_t off = (size_t)row * Hn + tid * 4;
  float4 v = *(const float4*)(x + off);
  float ss = v.x * v.x + v.y * v.y + v.z * v.z + v.w * v.w;
#pragma unroll
  for (int o = 32; o > 0; o >>= 1) ss += __shfl_xor(ss, o);
  __shared__ float ls[4];
  if ((tid & 63) == 0) ls[tid >> 6] = ss;
  __syncthreads();
  float tot = ls[0] + ls[1] + ls[2] + ls[3];
  float sc = rsqrtf(tot * (1.0f / Hn) + EPSf);
  float4 wv = *(const float4*)(w + tid * 4);
  float4 o4;
  o4.x = v.x * sc * wv.x; o4.y = v.y * sc * wv.y;
  o4.z = v.z * sc * wv.z; o4.w = v.w * sc * wv.w;
  *(float4*)(out + off) = o4;
}

// ---------------- residual add + RMSNorm (f32 outs + bf16 copy of t) ----------------
__global__ __launch_bounds__(256) void k_resid_norm(
    const float* __restrict__ x, const float* __restrict__ y,
    const float* __restrict__ w, float* __restrict__ x2out,
    float* __restrict__ tout, unsigned short* __restrict__ tbf) {
  int row = blockIdx.x, tid = threadIdx.x;
  size_t off = (size_t)row * Hn + tid * 4;
  float4 xv = *(const float4*)(x + off);
  float4 yv = *(const float4*)(y + off);
  float4 s;
  s.x = xv.x + yv.x; s.y = xv.y + yv.y; s.z = xv.z + yv.z; s.w = xv.w + yv.w;
  *(float4*)(x2out + off) = s;
  float ss = s.x * s.x + s.y * s.y + s.z * s.z + s.w * s.w;
#pragma unroll
  for (int o = 32; o > 0; o >>= 1) ss += __shfl_xor(ss, o);
  __shared__ float ls[4];
  if ((tid & 63) == 0) ls[tid >> 6] = ss;
  __syncthreads();
  float tot = ls[0] + ls[1] + ls[2] + ls[3];
  float sc = rsqrtf(tot * (1.0f / Hn) + EPSf);
  float4 wv4 = *(const float4*)(w + tid * 4);
  float4 t4;
  t4.x = s.x * sc * wv4.x; t4.y = s.y * sc * wv4.y;
  t4.z = s.z * sc * wv4.z; t4.w = s.w * sc * wv4.w;
  *(float4*)(tout + off) = t4;
  ushort4 b4;
  b4.x = f2bf(t4.x); b4.y = f2bf(t4.y); b4.z = f2bf(t4.z); b4.w = f2bf(t4.w);
  *(ushort4*)(tbf + off) = b4;
}

// ---------------- generic f32 GEMM: C(MxN) = A(MxK) @ B(KxN), 64x64 tile ----------------
__global__ __launch_bounds__(256) void k_gemm(
    const float* __restrict__ A, const float* __restrict__ B,
    float* __restrict__ C, int M, int N, int K) {
  __shared__ float As[16][68];
  __shared__ float Bs[16][64];
  int tid = threadIdx.x;
  int n0 = blockIdx.x * 64, m0 = blockIdx.y * 64;
  int tx = tid & 15, ty = tid >> 4;
  int arow = tid >> 2, ak = (tid & 3) * 4;
  int brow = tid >> 4, bcol = (tid & 15) * 4;
  float acc[4][4] = {};
  const float* Ap = A + (size_t)(m0 + arow) * K + ak;
  const float* Bp = B + (size_t)brow * N + n0 + bcol;
  for (int kb = 0; kb < K; kb += 16) {
    float4 a4 = *(const float4*)(Ap + kb);
    float4 b4 = *(const float4*)(Bp + (size_t)kb * N);
    __syncthreads();
    As[ak + 0][arow] = a4.x; As[ak + 1][arow] = a4.y;
    As[ak + 2][arow] = a4.z; As[ak + 3][arow] = a4.w;
    *(float4*)&Bs[brow][bcol] = b4;
    __syncthreads();
#pragma unroll
    for (int k = 0; k < 16; k++) {
      float4 av = *(const float4*)&As[k][ty * 4];
      float4 bv = *(const float4*)&Bs[k][tx * 4];
      float ar[4] = {av.x, av.y, av.z, av.w};
      float br[4] = {bv.x, bv.y, bv.z, bv.w};
#pragma unroll
      for (int i = 0; i < 4; i++)
#pragma unroll
        for (int j = 0; j < 4; j++)
          acc[i][j] = fmaf(ar[i], br[j], acc[i][j]);
    }
  }
#pragma unroll
  for (int i = 0; i < 4; i++) {
    float4 o4 = {acc[i][0], acc[i][1], acc[i][2], acc[i][3]};
    *(float4*)(C + (size_t)(m0 + ty * 4 + i) * N + n0 + tx * 4) = o4;
  }
}

// ---------------- q/k head-RMSNorm + RoPE, v transpose; writes k,v outputs ----------------
__global__ __launch_bounds__(256) void k_qkv_post(
    const float* __restrict__ q_raw, const float* __restrict__ k_raw,
    const float* __restrict__ v_raw, const float* __restrict__ qn_w,
    const float* __restrict__ kn_w, const float* __restrict__ freq,
    float* __restrict__ q_t, float* __restrict__ k_t, float* __restrict__ v_t,
    float* __restrict__ k_out, float* __restrict__ v_out) {
  int gw = blockIdx.x * 4 + (threadIdx.x >> 6);
  int lane = threadIdx.x & 63;
  int token = gw / 24;
  int hh = gw % 24;
  int b = token / Sn, s = token % Sn;
  if (hh >= 20) {  // v head: plain copy + transpose
    int h = hh - 20;
    float v = v_raw[(size_t)token * (HKVn * HDn) + h * HDn + lane];
    v_t[(((size_t)(b * HKVn + h)) * Sn + s) * HDn + lane] = v;
    v_out[(size_t)token * (HKVn * HDn) + h * HDn + lane] = v;
    return;
  }
  bool isq = hh < 16;
  int h = isq ? hh : hh - 16;
  float val = isq ? q_raw[(size_t)token * (HQn * HDn) + h * HDn + lane]
                  : k_raw[(size_t)token * (HKVn * HDn) + h * HDn + lane];
  float ss = val * val;
#pragma unroll
  for (int o = 32; o > 0; o >>= 1) ss += __shfl_xor(ss, o);
  float scn = rsqrtf(ss * (1.0f / HDn) + EPSf);
  float w = isq ? qn_w[lane] : kn_w[lane];
  float xn = val * scn * w;
  float f = freq[(size_t)s * (HDn / 2) + (lane & 31)];
  float c = cosf(f), sn = sinf(f);
  float partner = __shfl_xor(xn, 32);
  float out = (lane < 32) ? (xn * c - partner * sn) : (partner * sn + xn * c);
  if (isq) {
    q_t[(((size_t)(b * HQn + h)) * Sn + s) * HDn + lane] = out;
  } else {
    k_t[(((size_t)(b * HKVn + h)) * Sn + s) * HDn + lane] = out;
    k_out[(size_t)token * (HKVn * HDn) + h * HDn + lane] = out;
  }
}

// ---------------- causal GQA flash attention: 1 wave per query, 8 q/block ----------------
#define AQ 8
__global__ __launch_bounds__(512) void k_attn(
    const float* __restrict__ q_t, const float* __restrict__ k_t,
    const float* __restrict__ v_t, float* __restrict__ y) {
  __shared__ float Kt[HDn][65];
  __shared__ float Vs[64][65];
  __shared__ float qs[AQ][HDn];
  __shared__ float ps[AQ][64];
  int bid = blockIdx.x;
  int nqt = Sn / AQ;
  int qt = bid % nqt;
  int h = (bid / nqt) % HQn;
  int b = bid / (nqt * HQn);
  int kvh = h >> 2;
  int w = threadIdx.x >> 6, lane = threadIdx.x & 63;
  int q = qt * AQ + w;
  const float* Kp = k_t + ((size_t)(b * HKVn + kvh) * Sn) * HDn;
  const float* Vp = v_t + ((size_t)(b * HKVn + kvh) * Sn) * HDn;
  qs[w][lane] = q_t[(((size_t)(b * HQn + h)) * Sn + q) * HDn + lane];
  float m = -1e30f, l = 0.f, o = 0.f;
  int kmax = qt * AQ + (AQ - 1);
  for (int kk = 0; kk <= kmax; kk += 64) {
    __syncthreads();
#pragma unroll
    for (int rep = 0; rep < 2; rep++) {
      int vv = threadIdx.x + rep * 512;
      int row = vv >> 4;
      int d0 = (vv & 15) * 4;
      float4 k4 = *(const float4*)(Kp + (size_t)(kk + row) * HDn + d0);
      Kt[d0 + 0][row] = k4.x; Kt[d0 + 1][row] = k4.y;
      Kt[d0 + 2][row] = k4.z; Kt[d0 + 3][row] = k4.w;
      float4 v4 = *(const float4*)(Vp + (size_t)(kk + row) * HDn + d0);
      Vs[row][d0 + 0] = v4.x; Vs[row][d0 + 1] = v4.y;
      Vs[row][d0 + 2] = v4.z; Vs[row][d0 + 3] = v4.w;
    }
    __syncthreads();
    if (kk <= q) {
      float sc = 0.f;
#pragma unroll
      for (int d4 = 0; d4 < HDn; d4 += 4) {
        float4 q4 = *(const float4*)&qs[w][d4];
        sc = fmaf(q4.x, Kt[d4 + 0][lane], sc);
        sc = fmaf(q4.y, Kt[d4 + 1][lane], sc);
        sc = fmaf(q4.z, Kt[d4 + 2][lane], sc);
        sc = fmaf(q4.w, Kt[d4 + 3][lane], sc);
      }
      sc *= 0.125f;
      int key = kk + lane;
      if (key > q) sc = -1e30f;
      float mx = sc;
#pragma unroll
      for (int off = 32; off > 0; off >>= 1) mx = fmaxf(mx, __shfl_xor(mx, off));
      float mn = fmaxf(m, mx);
      float p = (key > q) ? 0.f : __expf(sc - mn);
      float rescale = __expf(m - mn);
      float psum = p;
#pragma unroll
      for (int off = 32; off > 0; off >>= 1) psum += __shfl_xor(psum, off);
      l = l * rescale + psum;
      m = mn;
      ps[w][lane] = p;
      o *= rescale;
#pragma unroll
      for (int k4 = 0; k4 < 64; k4 += 4) {
        float4 p4 = *(const float4*)&ps[w][k4];
        o = fmaf(p4.x, Vs[k4 + 0][lane], o);
        o = fmaf(p4.y, Vs[k4 + 1][lane], o);
        o = fmaf(p4.z, Vs[k4 + 2][lane], o);
        o = fmaf(p4.w, Vs[k4 + 3][lane], o);
      }
    }
  }
  y[((size_t)(b * Sn + q)) * (HQn * HDn) + h * HDn + lane] = o / l;
}

// ---------------- MoE router: softmax top-2, one wave per token (f32) ----------------
__global__ __launch_bounds__(256) void k_router(
    const float* __restrict__ t, const float* __restrict__ gw_,
    int* __restrict__ idx, float* __restrict__ val, int* __restrict__ cnt) {
  int tok = blockIdx.x * 4 + (threadIdx.x >> 6);
  int lane = threadIdx.x & 63;
  const float* tr = t + (size_t)tok * Hn;
  float s[8] = {0, 0, 0, 0, 0, 0, 0, 0};
  for (int hh = lane; hh < Hn; hh += 64) {
    float tv = tr[hh];
    float4 g0 = *(const float4*)(gw_ + hh * 8);
    float4 g1 = *(const float4*)(gw_ + hh * 8 + 4);
    s[0] = fmaf(tv, g0.x, s[0]); s[1] = fmaf(tv, g0.y, s[1]);
    s[2] = fmaf(tv, g0.z, s[2]); s[3] = fmaf(tv, g0.w, s[3]);
    s[4] = fmaf(tv, g1.x, s[4]); s[5] = fmaf(tv, g1.y, s[5]);
    s[6] = fmaf(tv, g1.z, s[6]); s[7] = fmaf(tv, g1.w, s[7]);
  }
#pragma unroll
  for (int e = 0; e < 8; e++)
#pragma unroll
    for (int off = 32; off > 0; off >>= 1) s[e] += __shfl_xor(s[e], off);
  if (lane == 0) {
    float mx = s[0];
    for (int e = 1; e < 8; e++) mx = fmaxf(mx, s[e]);
    float p[8];
    for (int e = 0; e < 8; e++) p[e] = __expf(s[e] - mx);
    int e0 = 0;
    for (int e = 1; e < 8; e++) if (p[e] > p[e0]) e0 = e;
    int e1 = (e0 == 0) ? 1 : 0;
    for (int e = 0; e < 8; e++) if (e != e0 && p[e] > p[e1]) e1 = e;
    float v0 = p[e0], v1 = p[e1], inv = 1.f / (v0 + v1);
    idx[tok * 2] = e0; idx[tok * 2 + 1] = e1;
    val[tok * 2] = v0 * inv; val[tok * 2 + 1] = v1 * inv;
    atomicAdd(&cnt[e0], 1); atomicAdd(&cnt[e1], 1);
  }
}

__global__ void k_scan(const int* __restrict__ cnt, int* __restrict__ offs,
                       int* __restrict__ cursor) {
  if (threadIdx.x == 0) {
    int run = 0;
    for (int e = 0; e < En; e++) { offs[e] = run; cursor[e] = run; run += cnt[e]; }
  }
}

__global__ __launch_bounds__(256) void k_scatter(
    const int* __restrict__ idx, const float* __restrict__ val,
    int* __restrict__ cursor, int* __restrict__ tokl, float* __restrict__ wvl) {
  int t = blockIdx.x * 256 + threadIdx.x;
#pragma unroll
  for (int slot = 0; slot < 2; slot++) {
    int e = idx[t * 2 + slot];
    int pos = atomicAdd(&cursor[e], 1);
    tokl[pos] = t;
    wvl[pos] = val[t * 2 + slot];
  }
}

// ---------------- gather token rows (bf16) into routed order ----------------
__global__ __launch_bounds__(256) void k_gather(
    const unsigned short* __restrict__ tb, const int* __restrict__ tokl,
    unsigned short* __restrict__ tg) {
  int r = blockIdx.x;
  int tk = tokl[r];
  const ushort4* s = (const ushort4*)(tb + (size_t)tk * Hn);
  ushort4* d = (ushort4*)(tg + (size_t)r * Hn);
  d[threadIdx.x] = s[threadIdx.x];
}

// ---------------- MoE GEMM1 (MFMA): ug[r][0:4096] = tg[r] @ w13t[e]^T ----------------
__global__ __launch_bounds__(256) void k_moe13(
    const unsigned short* __restrict__ tg, const unsigned short* __restrict__ w13t,
    unsigned short* __restrict__ ug, const int* __restrict__ cnt,
    const int* __restrict__ offs) {
  int e = blockIdx.z;
  int n_e = cnt[e];
  int mt = blockIdx.y;
  if (mt * 128 >= n_e) return;
  int base = offs[e];
  const unsigned short* A = tg + (size_t)(base + mt * 128) * Hn;
  const unsigned short* Bt = w13t + (size_t)e * (2 * In) * Hn;
  __shared__ __align__(16) short smA[4096];
  __shared__ __align__(16) short smB[4096];
  int tid = threadIdx.x;
  int wave = tid >> 6, lane = tid & 63;
  int n0 = blockIdx.x * 128;
  int wm = wave >> 1, wn = wave & 1;
  int s0 = tid, s1 = 256 + tid;
  int r0s = ((s0 >> 6) << 4) | (s0 & 15), k0s = ((s0 >> 4) & 3) * 8;
  int r1s = ((s1 >> 6) << 4) | (s1 & 15), k1s = ((s1 >> 4) & 3) * 8;
  const unsigned short* Ap0 = A + (size_t)r0s * Hn + k0s;
  const unsigned short* Ap1 = A + (size_t)r1s * Hn + k1s;
  const unsigned short* Bp0 = Bt + (size_t)(n0 + r0s) * Hn + k0s;
  const unsigned short* Bp1 = Bt + (size_t)(n0 + r1s) * Hn + k1s;
  short* lA0 = smA + (size_t)(wave * 64) * 8;
  short* lA1 = smA + (size_t)(256 + wave * 64) * 8;
  short* lB0 = smB + (size_t)(wave * 64) * 8;
  short* lB1 = smB + (size_t)(256 + wave * 64) * 8;
  f32x4 zf = {0.f, 0.f, 0.f, 0.f};
  f32x4 acc[4][4];
#pragma unroll
  for (int i = 0; i < 4; i++)
#pragma unroll
    for (int j = 0; j < 4; j++) acc[i][j] = zf;
  for (int kb = 0; kb < Hn; kb += 32) {
    __syncthreads();
    gll16(Ap0 + kb, lA0);
    gll16(Ap1 + kb, lA1);
    gll16(Bp0 + kb, lB0);
    gll16(Bp1 + kb, lB1);
    __syncthreads();
    bf16x8 af[4], bfr[4];
#pragma unroll
    for (int i = 0; i < 4; i++)
      af[i] = *(const bf16x8*)(smA + ((wm * 4 + i) * 64 + lane) * 8);
#pragma unroll
    for (int j = 0; j < 4; j++)
      bfr[j] = *(const bf16x8*)(smB + ((wn * 4 + j) * 64 + lane) * 8);
#pragma unroll
    for (int i = 0; i < 4; i++)
#pragma unroll
      for (int j = 0; j < 4; j++)
        acc[i][j] = __builtin_amdgcn_mfma_f32_16x16x32_bf16(af[i], bfr[j], acc[i][j], 0, 0, 0);
  }
  int cr = (lane >> 4) * 4, cc = lane & 15;
#pragma unroll
  for (int i = 0; i < 4; i++) {
    int lrow0 = (wm * 4 + i) * 16 + cr;
#pragma unroll
    for (int j = 0; j < 4; j++) {
      int ncol = n0 + (wn * 4 + j) * 16 + cc;
#pragma unroll
      for (int r = 0; r < 4; r++) {
        int rr = mt * 128 + lrow0 + r;
        if (rr < n_e)
          ug[(size_t)(base + rr) * (2 * In) + ncol] = f2bf(acc[i][j][r]);
      }
    }
  }
}

// ---------------- act = silu(u) * g ----------------
__global__ __launch_bounds__(256) void k_act(
    const unsigned short* __restrict__ ug, unsigned short* __restrict__ act) {
  size_t p = ((size_t)blockIdx.x * 256 + threadIdx.x) * 8;
  size_t r = p >> 11;
  int c = (int)(p & 2047);
  const ushort4* up = (const ushort4*)(ug + r * 4096 + c);
  const ushort4* gp = (const ushort4*)(ug + r * 4096 + 2048 + c);
  ushort4* ap = (ushort4*)(act + r * 2048 + c);
#pragma unroll
  for (int h = 0; h < 2; h++) {
    ushort4 uu = up[h], gg = gp[h];
    ushort4 oo;
    float u0 = bf2f(uu.x), u1 = bf2f(uu.y), u2 = bf2f(uu.z), u3 = bf2f(uu.w);
    oo.x = f2bf(u0 / (1.f + __expf(-u0)) * bf2f(gg.x));
    oo.y = f2bf(u1 / (1.f + __expf(-u1)) * bf2f(gg.y));
    oo.z = f2bf(u2 / (1.f + __expf(-u2)) * bf2f(gg.z));
    oo.w = f2bf(u3 / (1.f + __expf(-u3)) * bf2f(gg.w));
    ap[h] = oo;
  }
}

// ---------------- MoE GEMM2 (MFMA): out0 += gate * (act @ w2t[e]^T) ----------------
__global__ __launch_bounds__(256) void k_moe2(
    const unsigned short* __restrict__ act, const unsigned short* __restrict__ w2t,
    const int* __restrict__ cnt, const int* __restrict__ offs,
    const int* __restrict__ tokl, const float* __restrict__ wvl,
    float* __restrict__ out0) {
  int e = blockIdx.z;
  int n_e = cnt[e];
  int mt = blockIdx.y;
  if (mt * 128 >= n_e) return;
  int base = offs[e];
  __shared__ int ltok[128];
  __shared__ float lwv[128];
  int tid = threadIdx.x;
  if (tid < 128) {
    int rr = mt * 128 + tid;
    bool v = rr < n_e;
    ltok[tid] = v ? tokl[base + rr] : -1;
    lwv[tid] = v ? wvl[base + rr] : 0.f;
  }
  const unsigned short* A = act + (size_t)(base + mt * 128) * In;
  const unsigned short* Bt = w2t + (size_t)e * Hn * In;
  __shared__ __align__(16) short smA[4096];
  __shared__ __align__(16) short smB[4096];
  int wave = tid >> 6, lane = tid & 63;
  int n0 = blockIdx.x * 128;
  int wm = wave >> 1, wn = wave & 1;
  int s0 = tid, s1 = 256 + tid;
  int r0s = ((s0 >> 6) << 4) | (s0 & 15), k0s = ((s0 >> 4) & 3) * 8;
  int r1s = ((s1 >> 6) << 4) | (s1 & 15), k1s = ((s1 >> 4) & 3) * 8;
  const unsigned short* Ap0 = A + (size_t)r0s * In + k0s;
  const unsigned short* Ap1 = A + (size_t)r1s * In + k1s;
  const unsigned short* Bp0 = Bt + (size_t)(n0 + r0s) * In + k0s;
  const unsigned short* Bp1 = Bt + (size_t)(n0 + r1s) * In + k1s;
  short* lA0 = smA + (size_t)(wave * 64) * 8;
  short* lA1 = smA + (size_t)(256 + wave * 64) * 8;
  short* lB0 = smB + (size_t)(wave * 64) * 8;
  short* lB1 = smB + (size_t)(256 + wave * 64) * 8;
  f32x4 zf = {0.f, 0.f, 0.f, 0.f};
  f32x4 acc[4][4];
#pragma unroll
  for (int i = 0; i < 4; i++)
#pragma unroll
    for (int j = 0; j < 4; j++) acc[i][j] = zf;
  for (int kb = 0; kb < In; kb += 32) {
    __syncthreads();
    gll16(Ap0 + kb, lA0);
    gll16(Ap1 + kb, lA1);
    gll16(Bp0 + kb, lB0);
    gll16(Bp1 + kb, lB1);
    __syncthreads();
    bf16x8 af[4], bfr[4];
#pragma unroll
    for (int i = 0; i < 4; i++)
      af[i] = *(const bf16x8*)(smA + ((wm * 4 + i) * 64 + lane) * 8);
#pragma unroll
    for (int j = 0; j < 4; j++)
      bfr[j] = *(const bf16x8*)(smB + ((wn * 4 + j) * 64 + lane) * 8);
#pragma unroll
    for (int i = 0; i < 4; i++)
#pragma unroll
      for (int j = 0; j < 4; j++)
        acc[i][j] = __builtin_amdgcn_mfma_f32_16x16x32_bf16(af[i], bfr[j], acc[i][j], 0, 0, 0);
  }
  int cr = (lane >> 4) * 4, cc = lane & 15;
#pragma unroll
  for (int i = 0; i < 4; i++) {
    int lrow0 = (wm * 4 + i) * 16 + cr;
#pragma unroll
    for (int j = 0; j < 4; j++) {
      int ncol = n0 + (wn * 4 + j) * 16 + cc;
#pragma unroll
      for (int r = 0; r < 4; r++) {
        int lrow = lrow0 + r;
        int tk = ltok[lrow];
        if (tk >= 0)
          atomicAdd(out0 + (size_t)tk * Hn + ncol, lwv[lrow] * acc[i][j][r]);
      }
    }
  }
}

// ---------------- launch ----------------
extern "C" void kernel_launch(void* const* d_in, const int* in_sizes, int n_in,
                              void* d_out, int out_size, void* d_ws, size_t ws_size,
                              hipStream_t stream) {
  (void)in_sizes; (void)n_in; (void)out_size; (void)ws_size;
  const float* x      = (const float*)d_in[0];
  const float* freq   = (const float*)d_in[1];
  const float* n1w    = (const float*)d_in[2];
  const float* n2w    = (const float*)d_in[3];
  const float* wq     = (const float*)d_in[4];
  const float* wk     = (const float*)d_in[5];
  const float* wvp    = (const float*)d_in[6];
  const float* wo     = (const float*)d_in[7];
  const float* qn_w   = (const float*)d_in[8];
  const float* kn_w   = (const float*)d_in[9];
  const float* gate_w = (const float*)d_in[10];
  const float* w1     = (const float*)d_in[11];
  const float* w2     = (const float*)d_in[12];
  const float* w3     = (const float*)d_in[13];

  float* out0  = (float*)d_out;
  float* k_out = out0 + (size_t)Tn * Hn;
  float* v_out = k_out + (size_t)Tn * HKVn * HDn;

  char* wsb = (char*)d_ws;
  // MoE bf16 weights (transposed N x K)
  unsigned short* w13t = (unsigned short*)(wsb + 0);            // 8x4096x1024 = 64 MB
  unsigned short* w2t  = (unsigned short*)(wsb + 67108864);     // 8x1024x2048 = 32 MB
  unsigned short* tbf  = (unsigned short*)(wsb + 100663296);    // 2048x1024 bf16 (4 MB)
  unsigned short* tg   = (unsigned short*)(wsb + 104857600);    // 4096x1024 bf16 (8 MB)
  unsigned short* act  = (unsigned short*)(wsb + 113246208);    // 4096x2048 bf16 (16 MB)
  // U overlay @130,023,424: f32 attention path, later reused as ug (4096x4096 bf16 = 32 MB)
  float* hn    = (float*)(wsb + 130023424);                     // 8 MB
  float* q_raw = (float*)(wsb + 138412032);                     // 8 MB
  float* k_raw = (float*)(wsb + 146800640);                     // 2 MB
  float* v_raw = (float*)(wsb + 148897792);                     // 2 MB
  float* q_t   = (float*)(wsb + 150994944);                     // 8 MB
  float* k_t   = (float*)(wsb + 159383552);                     // 2 MB
  float* v_t   = (float*)(wsb + 161480704);                     // 2 MB
  unsigned short* ug = (unsigned short*)(wsb + 130023424);      // overlays hn..v_t (dead)
  float* y_att = (float*)(wsb + 163577856);                     // 8 MB (NOT overlaid by ug)
  float* y2    = (float*)(wsb + 171966464);                     // 8 MB
  // t_norm overlays q_t region: dead (router done) before ug written
  float* t_norm = (float*)(wsb + 150994944);
  char*  rtr   = wsb + 180355072;
  int*   idxb   = (int*)(rtr);
  float* valb   = (float*)(rtr + 16384);
  int*   cnt    = (int*)(rtr + 32768);
  int*   offs   = (int*)(rtr + 32768 + 128);
  int*   cursor = (int*)(rtr + 32768 + 256);
  int*   tokl   = (int*)(rtr + 32768 + 384);
  float* wvl    = (float*)(rtr + 32768 + 384 + 16384);

  // MoE weight transpose+cvt (w1,w3 -> w13t ; w2 -> w2t)
  k_tcvt<<<dim3(32, 16, 8), 256, 0, stream>>>(w1, w13t, 1024, 2048,
                                              (size_t)1024 * 2048, (size_t)4096 * 1024);
  k_tcvt<<<dim3(32, 16, 8), 256, 0, stream>>>(w3, w13t + (size_t)2048 * 1024, 1024, 2048,
                                              (size_t)1024 * 2048, (size_t)4096 * 1024);
  k_tcvt<<<dim3(16, 32, 8), 256, 0, stream>>>(w2, w2t, 2048, 1024,
                                              (size_t)2048 * 1024, (size_t)1024 * 2048);

  hipMemsetAsync(cnt, 0, 8 * sizeof(int), stream);

  // pre-router path: pure f32 (bit-identical to round-1 passing run)
  k_rmsnorm<<<Tn, 256, 0, stream>>>(x, n1w, hn);
  k_gemm<<<dim3(16, 32), 256, 0, stream>>>(hn, wq, q_raw, Tn, 1024, 1024);
  k_gemm<<<dim3(4, 32), 256, 0, stream>>>(hn, wk, k_raw, Tn, 256, 1024);
  k_gemm<<<dim3(4, 32), 256, 0, stream>>>(hn, wvp, v_raw, Tn, 256, 1024);
  k_qkv_post<<<(Tn * 24) / 4, 256, 0, stream>>>(q_raw, k_raw, v_raw, qn_w, kn_w,
                                                freq, q_t, k_t, v_t, k_out, v_out);
  k_attn<<<Bn * HQn * (Sn / AQ), 512, 0, stream>>>(q_t, k_t, v_t, y_att);
  k_gemm<<<dim3(16, 32), 256, 0, stream>>>(y_att, wo, y2, Tn, 1024, 1024);
  k_resid_norm<<<Tn, 256, 0, stream>>>(x, y2, n2w, out0, t_norm, tbf);
  k_router<<<Tn / 4, 256, 0, stream>>>(t_norm, gate_w, idxb, valb, cnt);
  k_scan<<<1, 64, 0, stream>>>(cnt, offs, cursor);
  k_scatter<<<Tn / 256, 256, 0, stream>>>(idxb, valb, cursor, tokl, wvl);
  k_gather<<<2 * Tn, 256, 0, stream>>>(tbf, tokl, tg);
  // MoE path: bf16 MFMA (smooth error only — routing already fixed)
  k_moe13<<<dim3(32, 16, 8), 256, 0, stream>>>(tg, w13t, ug, cnt, offs);
  k_act<<<4096, 256, 0, stream>>>(ug, act);
  k_moe2<<<dim3(8, 16, 8), 256, 0, stream>>>(act, w2t, cnt, offs, tokl, wvl, out0);
}

// Round 4
// 864.147 us; speedup vs baseline: 1.9186x; 1.3110x over previous
//
#include <hip/hip_runtime.h>
#include <hip/hip_bf16.h>

#define HQn 16
#define HKVn 4
#define HDn 64
#define Bn 2
#define Sn 1024
#define Hn 1024
#define En 8
#define In 2048
#define Tn 2048
#define EPSf 1e-6f

typedef __attribute__((ext_vector_type(8))) short bf16x8;
typedef __attribute__((ext_vector_type(4))) float f32x4;

// ---------------- helpers ----------------
__device__ __forceinline__ unsigned short f2bf(float f) {
  unsigned u = __float_as_uint(f);
  u += 0x7fffu + ((u >> 16) & 1u);
  return (unsigned short)(u >> 16);
}
__device__ __forceinline__ float bf2f(unsigned short u) {
  return __uint_as_float(((unsigned)u) << 16);
}
__device__ __forceinline__ void gll16(const void* g, void* l) {
  __builtin_amdgcn_global_load_lds(
      (const __attribute__((address_space(1))) void*)g,
      (__attribute__((address_space(3))) void*)l, 16, 0, 0);
}

// ---------------- transpose + f32->bf16: src[Z][R][C] -> dst[Z][C][R] ----------------
__global__ __launch_bounds__(256) void k_tcvt(
    const float* __restrict__ src, unsigned short* __restrict__ dst,
    int R, int C, size_t sZ, size_t dZ) {
  src += (size_t)blockIdx.z * sZ;
  dst += (size_t)blockIdx.z * dZ;
  int c0 = blockIdx.x * 64, r0 = blockIdx.y * 64;
  __shared__ float t[64][65];
  int tid = threadIdx.x;
  int lr = tid >> 4, lc = (tid & 15) * 4;
#pragma unroll
  for (int p = 0; p < 4; p++) {
    float4 v = *(const float4*)(src + (size_t)(r0 + lr + p * 16) * C + c0 + lc);
    t[lr + p * 16][lc + 0] = v.x; t[lr + p * 16][lc + 1] = v.y;
    t[lr + p * 16][lc + 2] = v.z; t[lr + p * 16][lc + 3] = v.w;
  }
  __syncthreads();
  int oc = tid >> 2;
  int seg = (tid & 3) * 16;
  unsigned pk[8];
#pragma unroll
  for (int j = 0; j < 8; j++) {
    unsigned short lo = f2bf(t[seg + 2 * j][oc]);
    unsigned short hi = f2bf(t[seg + 2 * j + 1][oc]);
    pk[j] = (unsigned)lo | ((unsigned)hi << 16);
  }
  uint4* dp = (uint4*)(dst + (size_t)(c0 + oc) * R + r0 + seg);
  dp[0] = make_uint4(pk[0], pk[1], pk[2], pk[3]);
  dp[1] = make_uint4(pk[4], pk[5], pk[6], pk[7]);
}

// ---------------- RMSNorm over H=1024, one block per row (f32 out) ----------------
__global__ __launch_bounds__(256) void k_rmsnorm(
    const float* __restrict__ x, const float* __restrict__ w,
    float* __restrict__ out) {
  int row = blockIdx.x, tid = threadIdx.x;
  size_t off = (size_t)row * Hn + tid * 4;
  float4 v = *(const float4*)(x + off);
  float ss = v.x * v.x + v.y * v.y + v.z * v.z + v.w * v.w;
#pragma unroll
  for (int o = 32; o > 0; o >>= 1) ss += __shfl_xor(ss, o);
  __shared__ float ls[4];
  if ((tid & 63) == 0) ls[tid >> 6] = ss;
  __syncthreads();
  float tot = ls[0] + ls[1] + ls[2] + ls[3];
  float sc = rsqrtf(tot * (1.0f / Hn) + EPSf);
  float4 wv = *(const float4*)(w + tid * 4);
  float4 o4;
  o4.x = v.x * sc * wv.x; o4.y = v.y * sc * wv.y;
  o4.z = v.z * sc * wv.z; o4.w = v.w * sc * wv.w;
  *(float4*)(out + off) = o4;
}

// ---------------- residual add + RMSNorm (f32 outs + bf16 copy of t) ----------------
__global__ __launch_bounds__(256) void k_resid_norm(
    const float* __restrict__ x, const float* __restrict__ y,
    const float* __restrict__ w, float* __restrict__ x2out,
    float* __restrict__ tout, unsigned short* __restrict__ tbf) {
  int row = blockIdx.x, tid = threadIdx.x;
  size_t off = (size_t)row * Hn + tid * 4;
  float4 xv = *(const float4*)(x + off);
  float4 yv = *(const float4*)(y + off);
  float4 s;
  s.x = xv.x + yv.x; s.y = xv.y + yv.y; s.z = xv.z + yv.z; s.w = xv.w + yv.w;
  *(float4*)(x2out + off) = s;
  float ss = s.x * s.x + s.y * s.y + s.z * s.z + s.w * s.w;
#pragma unroll
  for (int o = 32; o > 0; o >>= 1) ss += __shfl_xor(ss, o);
  __shared__ float ls[4];
  if ((tid & 63) == 0) ls[tid >> 6] = ss;
  __syncthreads();
  float tot = ls[0] + ls[1] + ls[2] + ls[3];
  float sc = rsqrtf(tot * (1.0f / Hn) + EPSf);
  float4 wv4 = *(const float4*)(w + tid * 4);
  float4 t4;
  t4.x = s.x * sc * wv4.x; t4.y = s.y * sc * wv4.y;
  t4.z = s.z * sc * wv4.z; t4.w = s.w * sc * wv4.w;
  *(float4*)(tout + off) = t4;
  ushort4 b4;
  b4.x = f2bf(t4.x); b4.y = f2bf(t4.y); b4.z = f2bf(t4.z); b4.w = f2bf(t4.w);
  *(ushort4*)(tbf + off) = b4;
}

// ---------------- generic f32 GEMM: C(MxN) = A(MxK) @ B(KxN), 64x64 tile ----------------
__global__ __launch_bounds__(256) void k_gemm(
    const float* __restrict__ A, const float* __restrict__ B,
    float* __restrict__ C, int M, int N, int K) {
  __shared__ float As[16][68];
  __shared__ float Bs[16][64];
  int tid = threadIdx.x;
  int n0 = blockIdx.x * 64, m0 = blockIdx.y * 64;
  int tx = tid & 15, ty = tid >> 4;
  int arow = tid >> 2, ak = (tid & 3) * 4;
  int brow = tid >> 4, bcol = (tid & 15) * 4;
  float acc[4][4] = {};
  const float* Ap = A + (size_t)(m0 + arow) * K + ak;
  const float* Bp = B + (size_t)brow * N + n0 + bcol;
  for (int kb = 0; kb < K; kb += 16) {
    float4 a4 = *(const float4*)(Ap + kb);
    float4 b4 = *(const float4*)(Bp + (size_t)kb * N);
    __syncthreads();
    As[ak + 0][arow] = a4.x; As[ak + 1][arow] = a4.y;
    As[ak + 2][arow] = a4.z; As[ak + 3][arow] = a4.w;
    *(float4*)&Bs[brow][bcol] = b4;
    __syncthreads();
#pragma unroll
    for (int k = 0; k < 16; k++) {
      float4 av = *(const float4*)&As[k][ty * 4];
      float4 bv = *(const float4*)&Bs[k][tx * 4];
      float ar[4] = {av.x, av.y, av.z, av.w};
      float br[4] = {bv.x, bv.y, bv.z, bv.w};
#pragma unroll
      for (int i = 0; i < 4; i++)
#pragma unroll
        for (int j = 0; j < 4; j++)
          acc[i][j] = fmaf(ar[i], br[j], acc[i][j]);
    }
  }
#pragma unroll
  for (int i = 0; i < 4; i++) {
    float4 o4 = {acc[i][0], acc[i][1], acc[i][2], acc[i][3]};
    *(float4*)(C + (size_t)(m0 + ty * 4 + i) * N + n0 + tx * 4) = o4;
  }
}

// ---------------- q/k head-RMSNorm + RoPE; emits q_t f32, K/V split-bf16 swizzled ----------------
// kT8 layout: [b][kvh][do=d>>3][s][d&7]  (8 consecutive d per s, per octet)
// vT8 layout: [b][kvh][ko=s>>3][d][s&7]  (8 consecutive s per d, per octet)
__global__ __launch_bounds__(256) void k_qkv_post(
    const float* __restrict__ q_raw, const float* __restrict__ k_raw,
    const float* __restrict__ v_raw, const float* __restrict__ qn_w,
    const float* __restrict__ kn_w, const float* __restrict__ freq,
    float* __restrict__ q_t,
    unsigned short* __restrict__ kT8h, unsigned short* __restrict__ kT8l,
    unsigned short* __restrict__ vT8h, unsigned short* __restrict__ vT8l,
    float* __restrict__ k_out, float* __restrict__ v_out) {
  int gw = blockIdx.x * 4 + (threadIdx.x >> 6);
  int lane = threadIdx.x & 63;
  int token = gw / 24;
  int hh = gw % 24;
  int b = token / Sn, s = token % Sn;
  if (hh >= 20) {  // v head
    int h = hh - 20;
    float v = v_raw[(size_t)token * (HKVn * HDn) + h * HDn + lane];
    unsigned short hi = f2bf(v);
    unsigned short lo = f2bf(v - bf2f(hi));
    size_t vb = (((size_t)(b * HKVn + h) * 128 + (s >> 3)) * 64 + lane) * 8 + (s & 7);
    vT8h[vb] = hi; vT8l[vb] = lo;
    v_out[(size_t)token * (HKVn * HDn) + h * HDn + lane] = v;
    return;
  }
  bool isq = hh < 16;
  int h = isq ? hh : hh - 16;
  float val = isq ? q_raw[(size_t)token * (HQn * HDn) + h * HDn + lane]
                  : k_raw[(size_t)token * (HKVn * HDn) + h * HDn + lane];
  float ss = val * val;
#pragma unroll
  for (int o = 32; o > 0; o >>= 1) ss += __shfl_xor(ss, o);
  float scn = rsqrtf(ss * (1.0f / HDn) + EPSf);
  float w = isq ? qn_w[lane] : kn_w[lane];
  float xn = val * scn * w;
  float f = freq[(size_t)s * (HDn / 2) + (lane & 31)];
  float c = cosf(f), sn = sinf(f);
  float partner = __shfl_xor(xn, 32);
  float out = (lane < 32) ? (xn * c - partner * sn) : (partner * sn + xn * c);
  if (isq) {
    q_t[(((size_t)(b * HQn + h)) * Sn + s) * HDn + lane] = out;
  } else {
    unsigned short hi = f2bf(out);
    unsigned short lo = f2bf(out - bf2f(hi));
    size_t kb = (((size_t)(b * HKVn + h) * 8 + (lane >> 3)) * Sn + s) * 8 + (lane & 7);
    kT8h[kb] = hi; kT8l[kb] = lo;
    k_out[(size_t)token * (HKVn * HDn) + h * HDn + lane] = out;
  }
}

// ---------------- MFMA flash attention, split-precision (hi/lo bf16 = ~f32 exact) ----
// block = (b, kvh, qt[16 rows]); wave w = head kvh*4+w. K/V chunk (64) shared in LDS.
__global__ __launch_bounds__(256) void k_attn_mfma(
    const float* __restrict__ q_t,
    const unsigned short* __restrict__ kT8h, const unsigned short* __restrict__ kT8l,
    const unsigned short* __restrict__ vT8h, const unsigned short* __restrict__ vT8l,
    float* __restrict__ y) {
  __shared__ __align__(16) unsigned short klh[4096], kll[4096];  // [do][key][din]
  __shared__ __align__(16) unsigned short vth[4096], vtl[4096];  // [ko][d][kin]
  __shared__ __align__(16) unsigned short Ph[4][1152], Pl[4][1152];  // [w][row][72]
  int bid = blockIdx.x;
  int qt = 63 - (bid & 63);       // long blocks first
  int kvh = (bid >> 6) & 3;
  int b = bid >> 8;
  int tid = threadIdx.x, w = tid >> 6, lane = tid & 63;
  int h = kvh * 4 + w;
  int g = lane >> 4, li = lane & 15;
  // Q A-frags: rows qt*16+li of head h, k = kc*32 + g*8 + j; split hi/lo
  const float* qrow = q_t + (((size_t)(b * HQn + h) * Sn) + qt * 16 + li) * HDn + g * 8;
  bf16x8 qh[2], ql[2];
#pragma unroll
  for (int kc = 0; kc < 2; kc++) {
    float v[8];
    *(float4*)(v) = *(const float4*)(qrow + kc * 32);
    *(float4*)(v + 4) = *(const float4*)(qrow + kc * 32 + 4);
#pragma unroll
    for (int j = 0; j < 8; j++) {
      unsigned short hi = f2bf(v[j]);
      qh[kc][j] = (short)hi;
      ql[kc][j] = (short)f2bf(v[j] - bf2f(hi));
    }
  }
  size_t bh = (size_t)(b * HKVn + kvh) * 65536;
  f32x4 acc[4];
  f32x4 zf = {0.f, 0.f, 0.f, 0.f};
#pragma unroll
  for (int nt = 0; nt < 4; nt++) acc[nt] = zf;
  float m_[4] = {-1e30f, -1e30f, -1e30f, -1e30f};
  float l_[4] = {0.f, 0.f, 0.f, 0.f};
  int rowb = qt * 16 + g * 4;
  int kmax = qt * 16 + 15;
  for (int kk = 0; kk <= kmax; kk += 64) {
    __syncthreads();
#pragma unroll
    for (int i = 0; i < 2; i++) {
      int idx = w * 2 + i;
      gll16(kT8h + bh + (size_t)idx * 8192 + (size_t)kk * 8 + lane * 8, &klh[idx * 512]);
      gll16(kT8l + bh + (size_t)idx * 8192 + (size_t)kk * 8 + lane * 8, &kll[idx * 512]);
      gll16(vT8h + bh + (size_t)(kk / 8 + idx) * 512 + lane * 8, &vth[idx * 512]);
      gll16(vT8l + bh + (size_t)(kk / 8 + idx) * 512 + lane * 8, &vtl[idx * 512]);
    }
    __syncthreads();
    // ---- scores: 4 key-tiles of 16 ----
    f32x4 st[4];
#pragma unroll
    for (int kt = 0; kt < 4; kt++) st[kt] = zf;
#pragma unroll
    for (int kt = 0; kt < 4; kt++)
#pragma unroll
      for (int kc = 0; kc < 2; kc++) {
        int ko = (kc * 4 + g) * 512 + (kt * 16 + li) * 8;
        bf16x8 kh = *(const bf16x8*)&klh[ko];
        bf16x8 klo = *(const bf16x8*)&kll[ko];
        st[kt] = __builtin_amdgcn_mfma_f32_16x16x32_bf16(qh[kc], kh, st[kt], 0, 0, 0);
        st[kt] = __builtin_amdgcn_mfma_f32_16x16x32_bf16(qh[kc], klo, st[kt], 0, 0, 0);
        st[kt] = __builtin_amdgcn_mfma_f32_16x16x32_bf16(ql[kc], kh, st[kt], 0, 0, 0);
      }
    // ---- online softmax (rows rowb..rowb+3 per lane) ----
    float mx[4] = {-1e30f, -1e30f, -1e30f, -1e30f};
#pragma unroll
    for (int kt = 0; kt < 4; kt++) {
      int key = kk + kt * 16 + li;
#pragma unroll
      for (int r = 0; r < 4; r++) {
        float s = st[kt][r] * 0.125f;
        if (key > rowb + r) s = -1e30f;
        st[kt][r] = s;
        mx[r] = fmaxf(mx[r], s);
      }
    }
#pragma unroll
    for (int r = 0; r < 4; r++) {
#pragma unroll
      for (int o = 1; o < 16; o <<= 1) mx[r] = fmaxf(mx[r], __shfl_xor(mx[r], o));
      float mn = fmaxf(m_[r], mx[r]);
      mx[r] = __expf(m_[r] - mn);  // alpha
      m_[r] = mn;
    }
    float rs[4] = {0.f, 0.f, 0.f, 0.f};
#pragma unroll
    for (int kt = 0; kt < 4; kt++)
#pragma unroll
      for (int r = 0; r < 4; r++) {
        float p = __expf(st[kt][r] - m_[r]);
        rs[r] += p;
        unsigned short phh = f2bf(p);
        Ph[w][(g * 4 + r) * 72 + kt * 16 + li] = phh;
        Pl[w][(g * 4 + r) * 72 + kt * 16 + li] = f2bf(p - bf2f(phh));
      }
#pragma unroll
    for (int r = 0; r < 4; r++) {
#pragma unroll
      for (int o = 1; o < 16; o <<= 1) rs[r] += __shfl_xor(rs[r], o);
      l_[r] = l_[r] * mx[r] + rs[r];
#pragma unroll
      for (int nt = 0; nt < 4; nt++) acc[nt][r] *= mx[r];
    }
    // ---- PV ----
    bf16x8 pfh[2], pfl[2];
#pragma unroll
    for (int kc = 0; kc < 2; kc++) {
      int po = li * 72 + kc * 32 + g * 8;
      pfh[kc] = *(const bf16x8*)&Ph[w][po];
      pfl[kc] = *(const bf16x8*)&Pl[w][po];
    }
#pragma unroll
    for (int nt = 0; nt < 4; nt++)
#pragma unroll
      for (int kc = 0; kc < 2; kc++) {
        int vo = (kc * 4 + g) * 512 + (nt * 16 + li) * 8;
        bf16x8 vh = *(const bf16x8*)&vth[vo];
        bf16x8 vl = *(const bf16x8*)&vtl[vo];
        acc[nt] = __builtin_amdgcn_mfma_f32_16x16x32_bf16(pfh[kc], vh, acc[nt], 0, 0, 0);
        acc[nt] = __builtin_amdgcn_mfma_f32_16x16x32_bf16(pfh[kc], vl, acc[nt], 0, 0, 0);
        acc[nt] = __builtin_amdgcn_mfma_f32_16x16x32_bf16(pfl[kc], vh, acc[nt], 0, 0, 0);
      }
  }
  float* yb = y + ((size_t)(b * Sn) + qt * 16) * (HQn * HDn) + h * HDn;
#pragma unroll
  for (int r = 0; r < 4; r++) {
    float inv = 1.f / l_[r];
#pragma unroll
    for (int nt = 0; nt < 4; nt++)
      yb[(size_t)(g * 4 + r) * (HQn * HDn) + nt * 16 + li] = acc[nt][r] * inv;
  }
}

// ---------------- MoE router: softmax top-2, one wave per token (f32) ----------------
__global__ __launch_bounds__(256) void k_router(
    const float* __restrict__ t, const float* __restrict__ gw_,
    int* __restrict__ idx, float* __restrict__ val, int* __restrict__ cnt) {
  int tok = blockIdx.x * 4 + (threadIdx.x >> 6);
  int lane = threadIdx.x & 63;
  const float* tr = t + (size_t)tok * Hn;
  float s[8] = {0, 0, 0, 0, 0, 0, 0, 0};
  for (int hh = lane; hh < Hn; hh += 64) {
    float tv = tr[hh];
    float4 g0 = *(const float4*)(gw_ + hh * 8);
    float4 g1 = *(const float4*)(gw_ + hh * 8 + 4);
    s[0] = fmaf(tv, g0.x, s[0]); s[1] = fmaf(tv, g0.y, s[1]);
    s[2] = fmaf(tv, g0.z, s[2]); s[3] = fmaf(tv, g0.w, s[3]);
    s[4] = fmaf(tv, g1.x, s[4]); s[5] = fmaf(tv, g1.y, s[5]);
    s[6] = fmaf(tv, g1.z, s[6]); s[7] = fmaf(tv, g1.w, s[7]);
  }
#pragma unroll
  for (int e = 0; e < 8; e++)
#pragma unroll
    for (int off = 32; off > 0; off >>= 1) s[e] += __shfl_xor(s[e], off);
  if (lane == 0) {
    float mx = s[0];
    for (int e = 1; e < 8; e++) mx = fmaxf(mx, s[e]);
    float p[8];
    for (int e = 0; e < 8; e++) p[e] = __expf(s[e] - mx);
    int e0 = 0;
    for (int e = 1; e < 8; e++) if (p[e] > p[e0]) e0 = e;
    int e1 = (e0 == 0) ? 1 : 0;
    for (int e = 0; e < 8; e++) if (e != e0 && p[e] > p[e1]) e1 = e;
    float v0 = p[e0], v1 = p[e1], inv = 1.f / (v0 + v1);
    idx[tok * 2] = e0; idx[tok * 2 + 1] = e1;
    val[tok * 2] = v0 * inv; val[tok * 2 + 1] = v1 * inv;
    atomicAdd(&cnt[e0], 1); atomicAdd(&cnt[e1], 1);
  }
}

__global__ void k_scan(const int* __restrict__ cnt, int* __restrict__ offs,
                       int* __restrict__ cursor) {
  if (threadIdx.x == 0) {
    int run = 0;
    for (int e = 0; e < En; e++) { offs[e] = run; cursor[e] = run; run += cnt[e]; }
  }
}

__global__ __launch_bounds__(256) void k_scatter(
    const int* __restrict__ idx, const float* __restrict__ val,
    int* __restrict__ cursor, int* __restrict__ tokl, float* __restrict__ wvl) {
  int t = blockIdx.x * 256 + threadIdx.x;
#pragma unroll
  for (int slot = 0; slot < 2; slot++) {
    int e = idx[t * 2 + slot];
    int pos = atomicAdd(&cursor[e], 1);
    tokl[pos] = t;
    wvl[pos] = val[t * 2 + slot];
  }
}

// ---------------- gather token rows (bf16) into routed order ----------------
__global__ __launch_bounds__(256) void k_gather(
    const unsigned short* __restrict__ tb, const int* __restrict__ tokl,
    unsigned short* __restrict__ tg) {
  int r = blockIdx.x;
  int tk = tokl[r];
  const ushort4* s = (const ushort4*)(tb + (size_t)tk * Hn);
  ushort4* d = (ushort4*)(tg + (size_t)r * Hn);
  d[threadIdx.x] = s[threadIdx.x];
}

// ---------------- MoE GEMM1 (MFMA): ug[r][0:4096] = tg[r] @ w13t[e]^T ----------------
__global__ __launch_bounds__(256) void k_moe13(
    const unsigned short* __restrict__ tg, const unsigned short* __restrict__ w13t,
    unsigned short* __restrict__ ug, const int* __restrict__ cnt,
    const int* __restrict__ offs) {
  int e = blockIdx.z;
  int n_e = cnt[e];
  int mt = blockIdx.y;
  if (mt * 128 >= n_e) return;
  int base = offs[e];
  const unsigned short* A = tg + (size_t)(base + mt * 128) * Hn;
  const unsigned short* Bt = w13t + (size_t)e * (2 * In) * Hn;
  __shared__ __align__(16) short smA[4096];
  __shared__ __align__(16) short smB[4096];
  int tid = threadIdx.x;
  int wave = tid >> 6, lane = tid & 63;
  int n0 = blockIdx.x * 128;
  int wm = wave >> 1, wn = wave & 1;
  int s0 = tid, s1 = 256 + tid;
  int r0s = ((s0 >> 6) << 4) | (s0 & 15), k0s = ((s0 >> 4) & 3) * 8;
  int r1s = ((s1 >> 6) << 4) | (s1 & 15), k1s = ((s1 >> 4) & 3) * 8;
  const unsigned short* Ap0 = A + (size_t)r0s * Hn + k0s;
  const unsigned short* Ap1 = A + (size_t)r1s * Hn + k1s;
  const unsigned short* Bp0 = Bt + (size_t)(n0 + r0s) * Hn + k0s;
  const unsigned short* Bp1 = Bt + (size_t)(n0 + r1s) * Hn + k1s;
  short* lA0 = smA + (size_t)(wave * 64) * 8;
  short* lA1 = smA + (size_t)(256 + wave * 64) * 8;
  short* lB0 = smB + (size_t)(wave * 64) * 8;
  short* lB1 = smB + (size_t)(256 + wave * 64) * 8;
  f32x4 zf = {0.f, 0.f, 0.f, 0.f};
  f32x4 acc[4][4];
#pragma unroll
  for (int i = 0; i < 4; i++)
#pragma unroll
    for (int j = 0; j < 4; j++) acc[i][j] = zf;
  for (int kb = 0; kb < Hn; kb += 32) {
    __syncthreads();
    gll16(Ap0 + kb, lA0);
    gll16(Ap1 + kb, lA1);
    gll16(Bp0 + kb, lB0);
    gll16(Bp1 + kb, lB1);
    __syncthreads();
    bf16x8 af[4], bfr[4];
#pragma unroll
    for (int i = 0; i < 4; i++)
      af[i] = *(const bf16x8*)(smA + ((wm * 4 + i) * 64 + lane) * 8);
#pragma unroll
    for (int j = 0; j < 4; j++)
      bfr[j] = *(const bf16x8*)(smB + ((wn * 4 + j) * 64 + lane) * 8);
#pragma unroll
    for (int i = 0; i < 4; i++)
#pragma unroll
      for (int j = 0; j < 4; j++)
        acc[i][j] = __builtin_amdgcn_mfma_f32_16x16x32_bf16(af[i], bfr[j], acc[i][j], 0, 0, 0);
  }
  int cr = (lane >> 4) * 4, cc = lane & 15;
#pragma unroll
  for (int i = 0; i < 4; i++) {
    int lrow0 = (wm * 4 + i) * 16 + cr;
#pragma unroll
    for (int j = 0; j < 4; j++) {
      int ncol = n0 + (wn * 4 + j) * 16 + cc;
#pragma unroll
      for (int r = 0; r < 4; r++) {
        int rr = mt * 128 + lrow0 + r;
        if (rr < n_e)
          ug[(size_t)(base + rr) * (2 * In) + ncol] = f2bf(acc[i][j][r]);
      }
    }
  }
}

// ---------------- act = silu(u) * g ----------------
__global__ __launch_bounds__(256) void k_act(
    const unsigned short* __restrict__ ug, unsigned short* __restrict__ act) {
  size_t p = ((size_t)blockIdx.x * 256 + threadIdx.x) * 8;
  size_t r = p >> 11;
  int c = (int)(p & 2047);
  const ushort4* up = (const ushort4*)(ug + r * 4096 + c);
  const ushort4* gp = (const ushort4*)(ug + r * 4096 + 2048 + c);
  ushort4* ap = (ushort4*)(act + r * 2048 + c);
#pragma unroll
  for (int h = 0; h < 2; h++) {
    ushort4 uu = up[h], gg = gp[h];
    ushort4 oo;
    float u0 = bf2f(uu.x), u1 = bf2f(uu.y), u2 = bf2f(uu.z), u3 = bf2f(uu.w);
    oo.x = f2bf(u0 / (1.f + __expf(-u0)) * bf2f(gg.x));
    oo.y = f2bf(u1 / (1.f + __expf(-u1)) * bf2f(gg.y));
    oo.z = f2bf(u2 / (1.f + __expf(-u2)) * bf2f(gg.z));
    oo.w = f2bf(u3 / (1.f + __expf(-u3)) * bf2f(gg.w));
    ap[h] = oo;
  }
}

// ---------------- MoE GEMM2 (MFMA): out0 += gate * (act @ w2t[e]^T) ----------------
__global__ __launch_bounds__(256) void k_moe2(
    const unsigned short* __restrict__ act, const unsigned short* __restrict__ w2t,
    const int* __restrict__ cnt, const int* __restrict__ offs,
    const int* __restrict__ tokl, const float* __restrict__ wvl,
    float* __restrict__ out0) {
  int e = blockIdx.z;
  int n_e = cnt[e];
  int mt = blockIdx.y;
  if (mt * 128 >= n_e) return;
  int base = offs[e];
  __shared__ int ltok[128];
  __shared__ float lwv[128];
  int tid = threadIdx.x;
  if (tid < 128) {
    int rr = mt * 128 + tid;
    bool v = rr < n_e;
    ltok[tid] = v ? tokl[base + rr] : -1;
    lwv[tid] = v ? wvl[base + rr] : 0.f;
  }
  const unsigned short* A = act + (size_t)(base + mt * 128) * In;
  const unsigned short* Bt = w2t + (size_t)e * Hn * In;
  __shared__ __align__(16) short smA[4096];
  __shared__ __align__(16) short smB[4096];
  int wave = tid >> 6, lane = tid & 63;
  int n0 = blockIdx.x * 128;
  int wm = wave >> 1, wn = wave & 1;
  int s0 = tid, s1 = 256 + tid;
  int r0s = ((s0 >> 6) << 4) | (s0 & 15), k0s = ((s0 >> 4) & 3) * 8;
  int r1s = ((s1 >> 6) << 4) | (s1 & 15), k1s = ((s1 >> 4) & 3) * 8;
  const unsigned short* Ap0 = A + (size_t)r0s * In + k0s;
  const unsigned short* Ap1 = A + (size_t)r1s * In + k1s;
  const unsigned short* Bp0 = Bt + (size_t)(n0 + r0s) * In + k0s;
  const unsigned short* Bp1 = Bt + (size_t)(n0 + r1s) * In + k1s;
  short* lA0 = smA + (size_t)(wave * 64) * 8;
  short* lA1 = smA + (size_t)(256 + wave * 64) * 8;
  short* lB0 = smB + (size_t)(wave * 64) * 8;
  short* lB1 = smB + (size_t)(256 + wave * 64) * 8;
  f32x4 zf = {0.f, 0.f, 0.f, 0.f};
  f32x4 acc[4][4];
#pragma unroll
  for (int i = 0; i < 4; i++)
#pragma unroll
    for (int j = 0; j < 4; j++) acc[i][j] = zf;
  for (int kb = 0; kb < In; kb += 32) {
    __syncthreads();
    gll16(Ap0 + kb, lA0);
    gll16(Ap1 + kb, lA1);
    gll16(Bp0 + kb, lB0);
    gll16(Bp1 + kb, lB1);
    __syncthreads();
    bf16x8 af[4], bfr[4];
#pragma unroll
    for (int i = 0; i < 4; i++)
      af[i] = *(const bf16x8*)(smA + ((wm * 4 + i) * 64 + lane) * 8);
#pragma unroll
    for (int j = 0; j < 4; j++)
      bfr[j] = *(const bf16x8*)(smB + ((wn * 4 + j) * 64 + lane) * 8);
#pragma unroll
    for (int i = 0; i < 4; i++)
#pragma unroll
      for (int j = 0; j < 4; j++)
        acc[i][j] = __builtin_amdgcn_mfma_f32_16x16x32_bf16(af[i], bfr[j], acc[i][j], 0, 0, 0);
  }
  int cr = (lane >> 4) * 4, cc = lane & 15;
#pragma unroll
  for (int i = 0; i < 4; i++) {
    int lrow0 = (wm * 4 + i) * 16 + cr;
#pragma unroll
    for (int j = 0; j < 4; j++) {
      int ncol = n0 + (wn * 4 + j) * 16 + cc;
#pragma unroll
      for (int r = 0; r < 4; r++) {
        int lrow = lrow0 + r;
        int tk = ltok[lrow];
        if (tk >= 0)
          atomicAdd(out0 + (size_t)tk * Hn + ncol, lwv[lrow] * acc[i][j][r]);
      }
    }
  }
}

// ---------------- launch ----------------
extern "C" void kernel_launch(void* const* d_in, const int* in_sizes, int n_in,
                              void* d_out, int out_size, void* d_ws, size_t ws_size,
                              hipStream_t stream) {
  (void)in_sizes; (void)n_in; (void)out_size; (void)ws_size;
  const float* x      = (const float*)d_in[0];
  const float* freq   = (const float*)d_in[1];
  const float* n1w    = (const float*)d_in[2];
  const float* n2w    = (const float*)d_in[3];
  const float* wq     = (const float*)d_in[4];
  const float* wk     = (const float*)d_in[5];
  const float* wvp    = (const float*)d_in[6];
  const float* wo     = (const float*)d_in[7];
  const float* qn_w   = (const float*)d_in[8];
  const float* kn_w   = (const float*)d_in[9];
  const float* gate_w = (const float*)d_in[10];
  const float* w1     = (const float*)d_in[11];
  const float* w2     = (const float*)d_in[12];
  const float* w3     = (const float*)d_in[13];

  float* out0  = (float*)d_out;
  float* k_out = out0 + (size_t)Tn * Hn;
  float* v_out = k_out + (size_t)Tn * HKVn * HDn;

  char* wsb = (char*)d_ws;
  unsigned short* w13t = (unsigned short*)(wsb + 0);            // 64 MB
  unsigned short* w2t  = (unsigned short*)(wsb + 67108864);     // 32 MB
  unsigned short* tbf  = (unsigned short*)(wsb + 100663296);    // 4 MB
  unsigned short* tg   = (unsigned short*)(wsb + 104857600);    // 8 MB
  unsigned short* act  = (unsigned short*)(wsb + 113246208);    // 16 MB
  // U overlay @130,023,424 (32 MB): f32 attention path, later reused as ug
  float* hn    = (float*)(wsb + 130023424);                     // 8 MB
  float* q_raw = (float*)(wsb + 138412032);                     // 8 MB
  float* k_raw = (float*)(wsb + 146800640);                     // 2 MB
  float* v_raw = (float*)(wsb + 148897792);                     // 2 MB
  float* q_t   = (float*)(wsb + 150994944);                     // 8 MB
  unsigned short* kT8h = (unsigned short*)(wsb + 159383552);    // 1 MB
  unsigned short* kT8l = (unsigned short*)(wsb + 160432128);    // 1 MB
  unsigned short* vT8h = (unsigned short*)(wsb + 161480704);    // 1 MB
  unsigned short* vT8l = (unsigned short*)(wsb + 162529280);    // 1 MB
  unsigned short* ug = (unsigned short*)(wsb + 130023424);      // overlays the above
  float* y_att = (float*)(wsb + 163577856);                     // 8 MB (not overlaid)
  float* y2    = (float*)(wsb + 171966464);                     // 8 MB
  float* t_norm = (float*)(wsb + 150994944);                    // overlays q_t (dead)
  char*  rtr   = wsb + 180355072;
  int*   idxb   = (int*)(rtr);
  float* valb   = (float*)(rtr + 16384);
  int*   cnt    = (int*)(rtr + 32768);
  int*   offs   = (int*)(rtr + 32768 + 128);
  int*   cursor = (int*)(rtr + 32768 + 256);
  int*   tokl   = (int*)(rtr + 32768 + 384);
  float* wvl    = (float*)(rtr + 32768 + 384 + 16384);

  k_tcvt<<<dim3(32, 16, 8), 256, 0, stream>>>(w1, w13t, 1024, 2048,
                                              (size_t)1024 * 2048, (size_t)4096 * 1024);
  k_tcvt<<<dim3(32, 16, 8), 256, 0, stream>>>(w3, w13t + (size_t)2048 * 1024, 1024, 2048,
                                              (size_t)1024 * 2048, (size_t)4096 * 1024);
  k_tcvt<<<dim3(16, 32, 8), 256, 0, stream>>>(w2, w2t, 2048, 1024,
                                              (size_t)2048 * 1024, (size_t)1024 * 2048);

  hipMemsetAsync(cnt, 0, 8 * sizeof(int), stream);

  k_rmsnorm<<<Tn, 256, 0, stream>>>(x, n1w, hn);
  k_gemm<<<dim3(16, 32), 256, 0, stream>>>(hn, wq, q_raw, Tn, 1024, 1024);
  k_gemm<<<dim3(4, 32), 256, 0, stream>>>(hn, wk, k_raw, Tn, 256, 1024);
  k_gemm<<<dim3(4, 32), 256, 0, stream>>>(hn, wvp, v_raw, Tn, 256, 1024);
  k_qkv_post<<<(Tn * 24) / 4, 256, 0, stream>>>(q_raw, k_raw, v_raw, qn_w, kn_w,
                                                freq, q_t, kT8h, kT8l, vT8h, vT8l,
                                                k_out, v_out);
  k_attn_mfma<<<Bn * HKVn * 64, 256, 0, stream>>>(q_t, kT8h, kT8l, vT8h, vT8l, y_att);
  k_gemm<<<dim3(16, 32), 256, 0, stream>>>(y_att, wo, y2, Tn, 1024, 1024);
  k_resid_norm<<<Tn, 256, 0, stream>>>(x, y2, n2w, out0, t_norm, tbf);
  k_router<<<Tn / 4, 256, 0, stream>>>(t_norm, gate_w, idxb, valb, cnt);
  k_scan<<<1, 64, 0, stream>>>(cnt, offs, cursor);
  k_scatter<<<Tn / 256, 256, 0, stream>>>(idxb, valb, cursor, tokl, wvl);
  k_gather<<<2 * Tn, 256, 0, stream>>>(tbf, tokl, tg);
  k_moe13<<<dim3(32, 16, 8), 256, 0, stream>>>(tg, w13t, ug, cnt, offs);
  k_act<<<4096, 256, 0, stream>>>(ug, act);
  k_moe2<<<dim3(8, 16, 8), 256, 0, stream>>>(act, w2t, cnt, offs, tokl, wvl, out0);
}